// Round 8
// baseline (142.647 us; speedup 1.0000x reference)
//
#include <hip/hip_runtime.h>
#include <cstdint>

typedef short  s16x8 __attribute__((ext_vector_type(8)));
typedef float  f32x4 __attribute__((ext_vector_type(4)));
typedef int    i32x4 __attribute__((ext_vector_type(4)));
typedef int    i32x2 __attribute__((ext_vector_type(2)));
typedef unsigned short u16x4 __attribute__((ext_vector_type(4)));

#define OUT_F 11008
#define IN_F  4096
#define MROWS 512
#define GQ4   176128   // i32x4 elements per W_q row (704512/4)
#define HALF  5504
#define RMOD  172

__device__ __forceinline__ unsigned short f2bf(float f) {
  unsigned u = __builtin_bit_cast(unsigned, f);
  return (unsigned short)((u + 0x8000u) >> 16);
}
__device__ __forceinline__ float bfbits(unsigned bits) {
  return __builtin_bit_cast(float, bits);
}
__device__ __forceinline__ unsigned cvtpk(float a, float b) {
  unsigned r;
  asm("v_cvt_pk_bf16_f32 %0, %1, %2" : "=v"(r) : "v"(a), "v"(b));
  return r;   // lo = bf16(a), hi = bf16(b)
}

// ---- prelude: bf16 x and U; f32 table mz = -(128+z)*s ----
__global__ __launch_bounds__(256) void convert_k(const float* __restrict__ x,
                                                 const float* __restrict__ U,
                                                 const float* __restrict__ scale,
                                                 const float* __restrict__ zero,
                                                 unsigned short* __restrict__ xbf,
                                                 unsigned short* __restrict__ Ubf,
                                                 f32x4* __restrict__ mz) {
  int i = blockIdx.x * 256 + threadIdx.x;
  const int NX = (MROWS * IN_F) / 4;   // 524288
  const int NU = (OUT_F * 32) / 4;     // 88064
  const int NS = 704512 / 4;           // 176128
  if (i < NX + NU) {
    const float* src; unsigned short* dst; int idx;
    if (i < NX) { src = x; dst = xbf; idx = i; }
    else        { src = U; dst = Ubf; idx = i - NX; }
    f32x4 v = *(const f32x4*)(src + (size_t)idx * 4);
    u16x4 o;
    o[0] = f2bf(v[0]); o[1] = f2bf(v[1]); o[2] = f2bf(v[2]); o[3] = f2bf(v[3]);
    *(u16x4*)(dst + (size_t)idx * 4) = o;
  } else {
    int idx = i - NX - NU;
    if (idx >= NS) return;
    f32x4 s = *(const f32x4*)(scale + (size_t)idx * 4);
    f32x4 z = *(const f32x4*)(zero  + (size_t)idx * 4);
    f32x4 m;
#pragma unroll
    for (int e = 0; e < 4; ++e) m[e] = -(z[e] + 128.f) * s[e];
    mz[idx] = m;
  }
}

// ---- prelude 2: P = x @ V^T (512x32), split-K atomics ----
__global__ __launch_bounds__(256) void pcalc_k(const float* __restrict__ x,
                                               const float* __restrict__ V,
                                               float* __restrict__ P) {
  int m  = (blockIdx.x >> 3) * 8 + (threadIdx.x >> 5);
  int j  = threadIdx.x & 31;
  int k0 = (blockIdx.x & 7) * 512;
  const float* xr = x + (size_t)m * IN_F + k0;
  const float* vr = V + (size_t)j * IN_F + k0;
  float a = 0.f;
#pragma unroll 4
  for (int k = 0; k < 512; k += 4) {
    f32x4 xv = *(const f32x4*)(xr + k);
    f32x4 vv = *(const f32x4*)(vr + k);
    a += xv[0]*vv[0] + xv[1]*vv[1] + xv[2]*vv[2] + xv[3]*vv[3];
  }
  atomicAdd(P + m * 32 + j, a);
}

// ---- main fused dequant GEMM ----
// Tile 128m x 64o, 512 threads (8 waves, 4m x 2o, 32x32 per wave).
// LDS 48KB: A dbuf [128][64]x2 + B dbuf [64][64]x2, XOR-swizzled.
// 3 blocks/CU x 8 waves = 24 waves/CU target occupancy (the round-8 lever).
// Grid 688 = 8 XCD x 86 contiguous-gn mapping (single-L2 W_q fetch).
__global__ __launch_bounds__(512, 6) void milo_gemm(
    const unsigned short* __restrict__ xbf,
    const i32x4*          __restrict__ Wq4,
    const f32x4*          __restrict__ Sc4,
    const f32x4*          __restrict__ Mz4,
    const float*          __restrict__ Pf,
    const i32x4*          __restrict__ Ubf4,
    const float*          __restrict__ bias,
    float*                __restrict__ out)
{
  extern __shared__ __align__(16) unsigned short smem[];
  // A bufs: smem + buf*8192 shorts; B bufs: smem + 16384 + buf*4096 shorts

  const int tid  = threadIdx.x;
  const int lane = tid & 63;
  const int wid  = tid >> 6;   // 0..7
  const int wm   = wid >> 1;   // 0..3: 32-row m sub-tile
  const int wn   = wid & 1;    // 0..1: 32-row B sub-tile

  const int b  = blockIdx.x;
  const int L  = (b & 7) * 86 + (b >> 3);
  const int gn = L >> 2;          // 0..171
  const int gm = L & 3;           // 0..3
  const int m0 = gm * 128;
  const int o0 = gn * 32;

  // ---- W staging offsets: one byte-row per thread (tr = tid>>4, 0..31) ----
  const int tr = tid >> 4;
  unsigned wq_off, sc_off;
  {
    int o = o0 + tr;
    int g = o / RMOD;
    int r = o - g * RMOD;
    wq_off = (unsigned)g * GQ4 + (unsigned)r * 1024u + (tid & 15);
    sc_off = (unsigned)r * 1024u + (tid & 15);
  }
  // ---- A staging: pre-swizzled global source, linear LDS dest ----
  unsigned a_src[2];
#pragma unroll
  for (int it = 0; it < 2; ++it) {
    int row   = wid * 16 + it * 8 + (lane >> 3);
    int chunk = (lane & 7) ^ (lane >> 3);
    a_src[it] = (unsigned)(m0 + row) * IN_F + chunk * 8;
  }

  const int akey   = (lane & 7) << 3;
  const int a_base = (wm * 32 + (lane & 15)) * 64 + ((lane >> 4) * 8);
  const int b_base = (wn * 32 + (lane & 15)) * 64 + ((lane >> 4) * 8);

  f32x4 acc[2][2];
  {
    f32x4 zf = {0.f, 0.f, 0.f, 0.f};
#pragma unroll
    for (int i = 0; i < 2; ++i)
#pragma unroll
      for (int j = 0; j < 2; ++j) acc[i][j] = zf;
  }

  i32x4 wq; f32x4 s4, mz4;
  f32x4 pf[2]; i32x4 uuF;

  auto issueA = [&](int buf, int k0s) {
    unsigned short* Adst = smem + buf * 8192;
#pragma unroll
    for (int it = 0; it < 2; ++it) {
      __builtin_amdgcn_global_load_lds(
          (const __attribute__((address_space(1))) unsigned int*)(xbf + a_src[it] + k0s),
          (__attribute__((address_space(3))) unsigned int*)(Adst + (wid * 16 + it * 8) * 64),
          16, 0, 0);
    }
  };
  auto loadB = [&](int kq) {   // kq in 16B units (16 per K-tile)
    wq  = Wq4[wq_off + kq];
    s4  = Sc4[sc_off + kq];
    mz4 = Mz4[sc_off + kq];
  };
  auto writeB = [&](int buf) {
    unsigned short* Bn = smem + 16384 + buf * 4096;
    int scol = ((tid & 15) * 4) ^ ((tr & 7) << 3);
    float h[4], l[4];
#pragma unroll
    for (int e = 0; e < 4; ++e) {
      int v = wq[e];
      // magic: 0x43000000 | (n<<16) is exactly f32(128+n) for n<16
      float qh = bfbits(0x43000000u | (((unsigned)v & 0xF0u) << 12));
      float ql = bfbits(0x43000000u | (((unsigned)v & 0x0Fu) << 16));
      h[e] = __builtin_fmaf(qh, s4[e], mz4[e]);
      l[e] = __builtin_fmaf(ql, s4[e], mz4[e]);
    }
    i32x2 hh = { (int)cvtpk(h[0], h[1]), (int)cvtpk(h[2], h[3]) };
    i32x2 ll = { (int)cvtpk(l[0], l[1]), (int)cvtpk(l[2], l[3]) };
    *(i32x2*)(Bn + tr * 64 + scol)        = hh;   // hi nibble -> o0+tr
    *(i32x2*)(Bn + (tr + 32) * 64 + scol) = ll;   // lo nibble -> o0+HALF+tr
  };
  auto loadF = [&]() {
    int row = tid >> 2, h4 = tid & 3;
#pragma unroll
    for (int q = 0; q < 2; ++q)
      pf[q] = *(const f32x4*)(Pf + (m0 + row) * 32 + h4 * 8 + q * 4);
    int rw = tid >> 3, h8 = tid & 7;
    int oc = (rw < 32) ? (o0 + rw) : (HALF + o0 + rw - 32);
    uuF = Ubf4[oc * 4 + (h8 & 3)];
  };
  auto writeF = [&](int buf) {
    unsigned short* An = smem + buf * 8192;
    unsigned short* Bn = smem + 16384 + buf * 4096;
    i32x4 zi = {0, 0, 0, 0};
    {
      int row = tid >> 2, h4 = tid & 3;
      int key = (row & 7) << 3;
      i32x4 t4 = { (int)cvtpk(pf[0][0], pf[0][1]), (int)cvtpk(pf[0][2], pf[0][3]),
                   (int)cvtpk(pf[1][0], pf[1][1]), (int)cvtpk(pf[1][2], pf[1][3]) };
      *(i32x4*)(An + row * 64 + ((h4 * 8) ^ key))      = t4;   // P cols 0..31
      *(i32x4*)(An + row * 64 + ((32 + h4 * 8) ^ key)) = zi;   // zero 32..63
    }
    {
      int rw = tid >> 3, h8 = tid & 7;
      int key = (rw & 7) << 3;
      *(i32x4*)(Bn + rw * 64 + ((h8 * 8) ^ key)) = (h8 < 4) ? uuF : zi;
    }
  };
  auto compute = [&](int buf) {
    const unsigned short* Ac = smem + buf * 8192;
    const unsigned short* Bc = smem + 16384 + buf * 4096;
    __builtin_amdgcn_s_setprio(1);
#pragma unroll
    for (int kk = 0; kk < 64; kk += 32) {
      s16x8 av[2], bv[2];
#pragma unroll
      for (int f = 0; f < 2; ++f)
        av[f] = *(const s16x8*)(Ac + ((a_base + f * 1024 + kk) ^ akey));
#pragma unroll
      for (int f = 0; f < 2; ++f)
        bv[f] = *(const s16x8*)(Bc + ((b_base + f * 1024 + kk) ^ akey));
#pragma unroll
      for (int i = 0; i < 2; ++i)
#pragma unroll
        for (int j = 0; j < 2; ++j)
          acc[i][j] = __builtin_amdgcn_mfma_f32_16x16x32_bf16(av[i], bv[j], acc[i][j], 0, 0, 0);
    }
    __builtin_amdgcn_s_setprio(0);
  };

  // ---- prologue: stage tile 0 ----
  loadB(0);
  issueA(0, 0);
  writeB(0);
  __syncthreads();

  // ---- main K loop: 64 tiles of BK=64 ----
  for (int t = 0; t < 63; ++t) {
    int cur = t & 1, nxt = cur ^ 1;
    loadB((t + 1) * 16);
    issueA(nxt, (t + 1) * 64);
    compute(cur);
    writeB(nxt);
    __syncthreads();
  }
  // ---- tile 63 + low-rank extra K-step ----
  loadF();
  compute(1);
  writeF(0);
  __syncthreads();
  compute(0);

  // ---- epilogue: bias + store ----
#pragma unroll
  for (int fn = 0; fn < 2; ++fn) {
    int c = wn * 32 + fn * 16 + (lane & 15);
    int o = (c < 32) ? (o0 + c) : (HALF + o0 + (c - 32));
    float bv = bias[o];
#pragma unroll
    for (int fm = 0; fm < 2; ++fm) {
      int m = m0 + wm * 32 + fm * 16 + ((lane >> 4) << 2);
#pragma unroll
      for (int j = 0; j < 4; ++j)
        out[(size_t)(m + j) * OUT_F + o] = acc[fm][fn][j] + bv;
    }
  }
}

extern "C" void kernel_launch(void* const* d_in, const int* in_sizes, int n_in,
                              void* d_out, int out_size, void* d_ws, size_t ws_size,
                              hipStream_t stream) {
  const float* x     = (const float*)d_in[0];
  const int*   Wq    = (const int*)d_in[1];
  const float* scale = (const float*)d_in[2];
  const float* zero  = (const float*)d_in[3];
  const float* U     = (const float*)d_in[4];
  const float* V     = (const float*)d_in[5];
  const float* bias  = (const float*)d_in[6];
  float* out = (float*)d_out;

  unsigned short* xbf = (unsigned short*)d_ws;                 // 4 MB
  unsigned short* Ubf = xbf + (size_t)MROWS * IN_F;            // 704 KB
  float*          P   = (float*)(Ubf + (size_t)OUT_F * 32);    // 64 KB
  float*          mz  = P + (size_t)MROWS * 32;                // 2.82 MB

  (void)hipMemsetAsync(P, 0, (size_t)MROWS * 32 * sizeof(float), stream);
  convert_k<<<3080, 256, 0, stream>>>(x, U, scale, zero, xbf, Ubf, (f32x4*)mz);
  pcalc_k<<<512, 256, 0, stream>>>(x, V, P);
  milo_gemm<<<688, 512, 49152, stream>>>(xbf, (const i32x4*)Wq,
                                         (const f32x4*)scale, (const f32x4*)mz,
                                         P, (const i32x4*)Ubf, bias, out);
}

// Round 11
// 137.321 us; speedup vs baseline: 1.0388x; 1.0388x over previous
//
#include <hip/hip_runtime.h>
#include <cstdint>

typedef short  s16x8 __attribute__((ext_vector_type(8)));
typedef float  f32x4 __attribute__((ext_vector_type(4)));
typedef int    i32x4 __attribute__((ext_vector_type(4)));
typedef int    i32x2 __attribute__((ext_vector_type(2)));
typedef unsigned short u16x4 __attribute__((ext_vector_type(4)));

#define OUT_F 11008
#define IN_F  4096
#define MROWS 512
#define GQ4   176128   // i32x4 elements per W_q row (704512/4)
#define HALF  5504
#define RMOD  172

__device__ __forceinline__ unsigned short f2bf(float f) {
  unsigned u = __builtin_bit_cast(unsigned, f);
  return (unsigned short)((u + 0x8000u) >> 16);
}
__device__ __forceinline__ float bfbits(unsigned bits) {
  return __builtin_bit_cast(float, bits);
}
__device__ __forceinline__ unsigned cvtpk(float a, float b) {
  unsigned r;
  asm("v_cvt_pk_bf16_f32 %0, %1, %2" : "=v"(r) : "v"(a), "v"(b));
  return r;   // lo = bf16(a), hi = bf16(b)
}

// ---- prelude: bf16-convert x and U ----
__global__ __launch_bounds__(256) void convert_k(const float* __restrict__ x,
                                                 const float* __restrict__ U,
                                                 unsigned short* __restrict__ xbf,
                                                 unsigned short* __restrict__ Ubf) {
  int i = blockIdx.x * 256 + threadIdx.x;
  const int NX = (MROWS * IN_F) / 4;   // 524288
  const int NU = (OUT_F * 32) / 4;     // 88064
  if (i >= NX + NU) return;
  const float* src; unsigned short* dst; int idx;
  if (i < NX) { src = x; dst = xbf; idx = i; }
  else        { src = U; dst = Ubf; idx = i - NX; }
  f32x4 v = *(const f32x4*)(src + (size_t)idx * 4);
  u16x4 o;
  o[0] = f2bf(v[0]); o[1] = f2bf(v[1]); o[2] = f2bf(v[2]); o[3] = f2bf(v[3]);
  *(u16x4*)(dst + (size_t)idx * 4) = o;
}

// ---- slow-path prelude: mz = -(z+128)*s table ----
__global__ __launch_bounds__(256) void mz_k(const float* __restrict__ scale,
                                            const float* __restrict__ zero,
                                            f32x4* __restrict__ mz) {
  int idx = blockIdx.x * 256 + threadIdx.x;
  if (idx >= 176128) return;
  f32x4 s = *(const f32x4*)(scale + (size_t)idx * 4);
  f32x4 z = *(const f32x4*)(zero  + (size_t)idx * 4);
  f32x4 m;
#pragma unroll
  for (int e = 0; e < 4; ++e) m[e] = -(z[e] + 128.f) * s[e];
  mz[idx] = m;
}

// ---- prelude 2: P = x @ V^T (512x32), split-K atomics ----
__global__ __launch_bounds__(256) void pcalc_k(const float* __restrict__ x,
                                               const float* __restrict__ V,
                                               float* __restrict__ P) {
  int m  = (blockIdx.x >> 3) * 8 + (threadIdx.x >> 5);
  int j  = threadIdx.x & 31;
  int k0 = (blockIdx.x & 7) * 512;
  const float* xr = x + (size_t)m * IN_F + k0;
  const float* vr = V + (size_t)j * IN_F + k0;
  float a = 0.f;
#pragma unroll 4
  for (int k = 0; k < 512; k += 4) {
    f32x4 xv = *(const f32x4*)(xr + k);
    f32x4 vv = *(const f32x4*)(vr + k);
    a += xv[0]*vv[0] + xv[1]*vv[1] + xv[2]*vv[2] + xv[3]*vv[3];
  }
  atomicAdd(P + m * 32 + j, a);
}

// ---- fast-path: full W dequant to bf16, PRE-SWIZZLED k-windows ----
// Wq byte-row j, group-col cc = r*4096+i -> output rows o=j*172+r (hi nibble)
// and o+5504 (lo nibble). Within-row chunk chL = i/8; store logical chunk at
// position (chL&~7)|((chL^o)&7) so the GEMM's linear global_load_lds +
// XOR-read (key = lane&7 = o&7) recovers it.
__global__ __launch_bounds__(256) void wdeq_k(const i32x4* __restrict__ Wq4,
                                              const float* __restrict__ scale,
                                              const float* __restrict__ zero,
                                              unsigned short* __restrict__ Wbf) {
  int n  = blockIdx.x * 256 + threadIdx.x;   // 352256 total
  int jo = n / 88064;                        // 0..3 (j-octet)
  int ch = n - jo * 88064;                   // 8-int32 chunk id, cc0 = ch*8
  int r  = ch >> 9;                          // 0..171
  const int chL = ch & 511;                  // within-row chunk (i = chL*8)
  const int cc0 = ch * 8;
  f32x4 s0 = *(const f32x4*)(scale + cc0);
  f32x4 s1 = *(const f32x4*)(scale + cc0 + 4);
  f32x4 z0 = *(const f32x4*)(zero + cc0);
  f32x4 z1 = *(const f32x4*)(zero + cc0 + 4);
  float sv[8], mzv[8];
#pragma unroll
  for (int e = 0; e < 4; ++e) {
    sv[e]      = s0[e]; mzv[e]     = -(z0[e] + 128.f) * s0[e];
    sv[e + 4]  = s1[e]; mzv[e + 4] = -(z1[e] + 128.f) * s1[e];
  }
#pragma unroll
  for (int jj = 0; jj < 8; ++jj) {
    int j = jo * 8 + jj;
    i32x4 w0 = Wq4[(size_t)j * GQ4 + ch * 2];
    i32x4 w1 = Wq4[(size_t)j * GQ4 + ch * 2 + 1];
    float h[8], l[8];
#pragma unroll
    for (int e = 0; e < 8; ++e) {
      int v = (e < 4) ? w0[e] : w1[e - 4];
      float qh = bfbits(0x43000000u | (((unsigned)v & 0xF0u) << 12));
      float ql = bfbits(0x43000000u | (((unsigned)v & 0x0Fu) << 16));
      h[e] = __builtin_fmaf(qh, sv[e], mzv[e]);
      l[e] = __builtin_fmaf(ql, sv[e], mzv[e]);
    }
    i32x4 hh = { (int)cvtpk(h[0], h[1]), (int)cvtpk(h[2], h[3]),
                 (int)cvtpk(h[4], h[5]), (int)cvtpk(h[6], h[7]) };
    i32x4 ll = { (int)cvtpk(l[0], l[1]), (int)cvtpk(l[2], l[3]),
                 (int)cvtpk(l[4], l[5]), (int)cvtpk(l[6], l[7]) };
    int o  = j * RMOD + r;
    int o2 = o + HALF;
    unsigned sc  = ((unsigned)chL & ~7u) | (((unsigned)chL ^ (unsigned)o)  & 7u);
    unsigned sc2 = ((unsigned)chL & ~7u) | (((unsigned)chL ^ (unsigned)o2) & 7u);
    *(i32x4*)(Wbf + (size_t)o  * IN_F + sc  * 8) = hh;
    *(i32x4*)(Wbf + (size_t)o2 * IN_F + sc2 * 8) = ll;
  }
}

// ---- fast-path GEMM: pure bf16, tile 64m x 128o, 512 thr (8 waves 2x4) ----
// LDS 48KB: A [64][64]x2 (16KB) + B [128][64]x2 (32KB). A: pre-swizzled
// source; B: Wbf pre-swizzled in memory -> both staged via linear
// global_load_lds, both read with XOR key. Grid 688 = 8 XCD x 86.
__global__ __launch_bounds__(512, 6) void gemm_fast(
    const unsigned short* __restrict__ xbf,
    const unsigned short* __restrict__ Wbf,
    const float*          __restrict__ Pf,
    const i32x4*          __restrict__ Ubf4,
    const float*          __restrict__ bias,
    float*                __restrict__ out)
{
  extern __shared__ __align__(16) unsigned short smem[];
  // A bufs: smem + buf*4096 shorts; B bufs: smem + 8192 + buf*8192 shorts

  const int tid  = threadIdx.x;
  const int lane = tid & 63;
  const int wid  = tid >> 6;   // 0..7
  const int wm   = wid >> 2;   // 0..1: 32-row m sub-tile
  const int wn   = wid & 3;    // 0..3: 32-row o sub-tile

  const int b  = blockIdx.x;
  const int L  = (b & 7) * 86 + (b >> 3);
  const int gn = L >> 3;          // 0..85  -> o0 = gn*128
  const int gm = L & 7;           // 0..7   -> m0 = gm*64
  const int m0 = gm * 64;
  const int o0 = gn * 128;

  // A staging: pre-swizzled global source, linear LDS dest (tid*8 shorts)
  const int arow = tid >> 3;
  const unsigned a_src = (unsigned)(m0 + arow) * IN_F +
                         (((tid & 7) ^ (arow & 7)) * 8);
  // B staging: Wbf already swizzled -> linear source, linear dest
  size_t b_src[2];
#pragma unroll
  for (int it = 0; it < 2; ++it)
    b_src[it] = (size_t)(o0 + it * 64 + (tid >> 3)) * IN_F + (tid & 7) * 8;

  const int akey   = (lane & 7) << 3;
  const int a_base = (wm * 32 + (lane & 15)) * 64 + ((lane >> 4) * 8);
  const int b_base = (wn * 32 + (lane & 15)) * 64 + ((lane >> 4) * 8);

  f32x4 acc[2][2];
  {
    f32x4 zf = {0.f, 0.f, 0.f, 0.f};
#pragma unroll
    for (int i = 0; i < 2; ++i)
#pragma unroll
      for (int j = 0; j < 2; ++j) acc[i][j] = zf;
  }
  f32x4 pf0, pf1; i32x4 uuF;

  auto issueA = [&](int buf, int k0s) {
    unsigned short* Adst = smem + buf * 4096;
    __builtin_amdgcn_global_load_lds(
        (const __attribute__((address_space(1))) unsigned int*)(xbf + a_src + k0s),
        (__attribute__((address_space(3))) unsigned int*)(Adst + tid * 8),
        16, 0, 0);
  };
  auto issueB = [&](int buf, int k0s) {
    unsigned short* Bdst = smem + 8192 + buf * 8192;
#pragma unroll
    for (int it = 0; it < 2; ++it) {
      __builtin_amdgcn_global_load_lds(
          (const __attribute__((address_space(1))) unsigned int*)(Wbf + b_src[it] + k0s),
          (__attribute__((address_space(3))) unsigned int*)(Bdst + it * 4096 + tid * 8),
          16, 0, 0);
    }
  };
  auto compute = [&](int buf) {
    const unsigned short* Ac = smem + buf * 4096;
    const unsigned short* Bc = smem + 8192 + buf * 8192;
    __builtin_amdgcn_s_setprio(1);
#pragma unroll
    for (int kk = 0; kk < 64; kk += 32) {
      s16x8 av[2], bv[2];
#pragma unroll
      for (int f = 0; f < 2; ++f)
        av[f] = *(const s16x8*)(Ac + ((a_base + f * 1024 + kk) ^ akey));
#pragma unroll
      for (int f = 0; f < 2; ++f)
        bv[f] = *(const s16x8*)(Bc + ((b_base + f * 1024 + kk) ^ akey));
#pragma unroll
      for (int i = 0; i < 2; ++i)
#pragma unroll
        for (int j = 0; j < 2; ++j)
          acc[i][j] = __builtin_amdgcn_mfma_f32_16x16x32_bf16(av[i], bv[j], acc[i][j], 0, 0, 0);
    }
    __builtin_amdgcn_s_setprio(0);
  };
  auto loadF = [&]() {
    int row = tid >> 3, h8 = tid & 7;
    if (h8 < 4) {
      pf0 = *(const f32x4*)(Pf + (m0 + row) * 32 + h8 * 8);
      pf1 = *(const f32x4*)(Pf + (m0 + row) * 32 + h8 * 8 + 4);
    }
    int rw = tid >> 2, h4 = tid & 3;
    uuF = Ubf4[(size_t)(o0 + rw) * 4 + h4];
  };
  auto writeF = [&](int buf) {
    unsigned short* An = smem + buf * 4096;
    unsigned short* Bn = smem + 8192 + buf * 8192;
    i32x4 zi = {0, 0, 0, 0};
    {
      int row = tid >> 3, h8 = tid & 7, key = row & 7;
      i32x4 v = zi;
      if (h8 < 4)
        v = i32x4{ (int)cvtpk(pf0[0], pf0[1]), (int)cvtpk(pf0[2], pf0[3]),
                   (int)cvtpk(pf1[0], pf1[1]), (int)cvtpk(pf1[2], pf1[3]) };
      *(i32x4*)(An + row * 64 + ((h8 ^ key) * 8)) = v;
    }
    {
      int rw = tid >> 2, h4 = tid & 3, key = rw & 7;
      *(i32x4*)(Bn + rw * 64 + ((h4 ^ key) * 8))       = uuF;
      *(i32x4*)(Bn + rw * 64 + (((h4 + 4) ^ key) * 8)) = zi;
    }
  };

  // ---- prologue ----
  issueA(0, 0);
  issueB(0, 0);
  __syncthreads();

  // ---- main K loop: 64 tiles of BK=64 ----
  for (int t = 0; t < 63; ++t) {
    int cur = t & 1, nxt = cur ^ 1;
    issueA(nxt, (t + 1) * 64);
    issueB(nxt, (t + 1) * 64);
    compute(cur);
    __syncthreads();
  }
  // ---- tile 63 + low-rank extra K-step ----
  loadF();
  compute(1);
  writeF(0);
  __syncthreads();
  compute(0);

  // ---- epilogue: bias + store (no HALF pairing: Wbf in final row order) ----
#pragma unroll
  for (int fn = 0; fn < 2; ++fn) {
    int o = o0 + wn * 32 + fn * 16 + (lane & 15);
    float bv = bias[o];
#pragma unroll
    for (int fm = 0; fm < 2; ++fm) {
      int m = m0 + wm * 32 + fm * 16 + ((lane >> 4) << 2);
#pragma unroll
      for (int j = 0; j < 4; ++j)
        out[(size_t)(m + j) * OUT_F + o] = acc[fm][fn][j] + bv;
    }
  }
}

// ================= slow-path fallback: round-8 fused kernel =================
__global__ __launch_bounds__(512, 6) void milo_gemm(
    const unsigned short* __restrict__ xbf,
    const i32x4*          __restrict__ Wq4,
    const f32x4*          __restrict__ Sc4,
    const f32x4*          __restrict__ Mz4,
    const float*          __restrict__ Pf,
    const i32x4*          __restrict__ Ubf4,
    const float*          __restrict__ bias,
    float*                __restrict__ out)
{
  extern __shared__ __align__(16) unsigned short smem[];
  const int tid  = threadIdx.x;
  const int lane = tid & 63;
  const int wid  = tid >> 6;
  const int wm   = wid >> 1;
  const int wn   = wid & 1;
  const int b  = blockIdx.x;
  const int L  = (b & 7) * 86 + (b >> 3);
  const int gn = L >> 2;
  const int gm = L & 3;
  const int m0 = gm * 128;
  const int o0 = gn * 32;
  const int tr = tid >> 4;
  unsigned wq_off, sc_off;
  {
    int o = o0 + tr;
    int g = o / RMOD;
    int r = o - g * RMOD;
    wq_off = (unsigned)g * GQ4 + (unsigned)r * 1024u + (tid & 15);
    sc_off = (unsigned)r * 1024u + (tid & 15);
  }
  unsigned a_src[2];
#pragma unroll
  for (int it = 0; it < 2; ++it) {
    int row   = wid * 16 + it * 8 + (lane >> 3);
    int chunk = (lane & 7) ^ (lane >> 3);
    a_src[it] = (unsigned)(m0 + row) * IN_F + chunk * 8;
  }
  const int akey   = (lane & 7) << 3;
  const int a_base = (wm * 32 + (lane & 15)) * 64 + ((lane >> 4) * 8);
  const int b_base = (wn * 32 + (lane & 15)) * 64 + ((lane >> 4) * 8);
  f32x4 acc[2][2];
  {
    f32x4 zf = {0.f, 0.f, 0.f, 0.f};
#pragma unroll
    for (int i = 0; i < 2; ++i)
#pragma unroll
      for (int j = 0; j < 2; ++j) acc[i][j] = zf;
  }
  i32x4 wq; f32x4 s4, mz4;
  f32x4 pf[2]; i32x4 uuF;
  auto issueA = [&](int buf, int k0s) {
    unsigned short* Adst = smem + buf * 8192;
#pragma unroll
    for (int it = 0; it < 2; ++it) {
      __builtin_amdgcn_global_load_lds(
          (const __attribute__((address_space(1))) unsigned int*)(xbf + a_src[it] + k0s),
          (__attribute__((address_space(3))) unsigned int*)(Adst + (wid * 16 + it * 8) * 64),
          16, 0, 0);
    }
  };
  auto loadB = [&](int kq) {
    wq  = Wq4[wq_off + kq];
    s4  = Sc4[sc_off + kq];
    mz4 = Mz4[sc_off + kq];
  };
  auto writeB = [&](int buf) {
    unsigned short* Bn = smem + 16384 + buf * 4096;
    int scol = ((tid & 15) * 4) ^ ((tr & 7) << 3);
    float h[4], l[4];
#pragma unroll
    for (int e = 0; e < 4; ++e) {
      int v = wq[e];
      float qh = bfbits(0x43000000u | (((unsigned)v & 0xF0u) << 12));
      float ql = bfbits(0x43000000u | (((unsigned)v & 0x0Fu) << 16));
      h[e] = __builtin_fmaf(qh, s4[e], mz4[e]);
      l[e] = __builtin_fmaf(ql, s4[e], mz4[e]);
    }
    i32x2 hh = { (int)cvtpk(h[0], h[1]), (int)cvtpk(h[2], h[3]) };
    i32x2 ll = { (int)cvtpk(l[0], l[1]), (int)cvtpk(l[2], l[3]) };
    *(i32x2*)(Bn + tr * 64 + scol)        = hh;
    *(i32x2*)(Bn + (tr + 32) * 64 + scol) = ll;
  };
  auto loadF = [&]() {
    int row = tid >> 2, h4 = tid & 3;
#pragma unroll
    for (int q = 0; q < 2; ++q)
      pf[q] = *(const f32x4*)(Pf + (m0 + row) * 32 + h4 * 8 + q * 4);
    int rw = tid >> 3, h8 = tid & 7;
    int oc = (rw < 32) ? (o0 + rw) : (HALF + o0 + rw - 32);
    uuF = Ubf4[oc * 4 + (h8 & 3)];
  };
  auto writeF = [&](int buf) {
    unsigned short* An = smem + buf * 8192;
    unsigned short* Bn = smem + 16384 + buf * 4096;
    i32x4 zi = {0, 0, 0, 0};
    {
      int row = tid >> 2, h4 = tid & 3;
      int key = (row & 7) << 3;
      i32x4 t4 = { (int)cvtpk(pf[0][0], pf[0][1]), (int)cvtpk(pf[0][2], pf[0][3]),
                   (int)cvtpk(pf[1][0], pf[1][1]), (int)cvtpk(pf[1][2], pf[1][3]) };
      *(i32x4*)(An + row * 64 + ((h4 * 8) ^ key))      = t4;
      *(i32x4*)(An + row * 64 + ((32 + h4 * 8) ^ key)) = zi;
    }
    {
      int rw = tid >> 3, h8 = tid & 7;
      int key = (rw & 7) << 3;
      *(i32x4*)(Bn + rw * 64 + ((h8 * 8) ^ key)) = (h8 < 4) ? uuF : zi;
    }
  };
  auto compute = [&](int buf) {
    const unsigned short* Ac = smem + buf * 8192;
    const unsigned short* Bc = smem + 16384 + buf * 4096;
    __builtin_amdgcn_s_setprio(1);
#pragma unroll
    for (int kk = 0; kk < 64; kk += 32) {
      s16x8 av[2], bv[2];
#pragma unroll
      for (int f = 0; f < 2; ++f)
        av[f] = *(const s16x8*)(Ac + ((a_base + f * 1024 + kk) ^ akey));
#pragma unroll
      for (int f = 0; f < 2; ++f)
        bv[f] = *(const s16x8*)(Bc + ((b_base + f * 1024 + kk) ^ akey));
#pragma unroll
      for (int i = 0; i < 2; ++i)
#pragma unroll
        for (int j = 0; j < 2; ++j)
          acc[i][j] = __builtin_amdgcn_mfma_f32_16x16x32_bf16(av[i], bv[j], acc[i][j], 0, 0, 0);
    }
    __builtin_amdgcn_s_setprio(0);
  };
  loadB(0);
  issueA(0, 0);
  writeB(0);
  __syncthreads();
  for (int t = 0; t < 63; ++t) {
    int cur = t & 1, nxt = cur ^ 1;
    loadB((t + 1) * 16);
    issueA(nxt, (t + 1) * 64);
    compute(cur);
    writeB(nxt);
    __syncthreads();
  }
  loadF();
  compute(1);
  writeF(0);
  __syncthreads();
  compute(0);
#pragma unroll
  for (int fn = 0; fn < 2; ++fn) {
    int c = wn * 32 + fn * 16 + (lane & 15);
    int o = (c < 32) ? (o0 + c) : (HALF + o0 + (c - 32));
    float bv = bias[o];
#pragma unroll
    for (int fm = 0; fm < 2; ++fm) {
      int m = m0 + wm * 32 + fm * 16 + ((lane >> 4) << 2);
#pragma unroll
      for (int j = 0; j < 4; ++j)
        out[(size_t)(m + j) * OUT_F + o] = acc[fm][fn][j] + bv;
    }
  }
}

extern "C" void kernel_launch(void* const* d_in, const int* in_sizes, int n_in,
                              void* d_out, int out_size, void* d_ws, size_t ws_size,
                              hipStream_t stream) {
  const float* x     = (const float*)d_in[0];
  const int*   Wq    = (const int*)d_in[1];
  const float* scale = (const float*)d_in[2];
  const float* zero  = (const float*)d_in[3];
  const float* U     = (const float*)d_in[4];
  const float* V     = (const float*)d_in[5];
  const float* bias  = (const float*)d_in[6];
  float* out = (float*)d_out;

  unsigned short* xbf = (unsigned short*)d_ws;                 // 4 MB
  unsigned short* Ubf = xbf + (size_t)MROWS * IN_F;            // 704 KB
  float*          P   = (float*)(Ubf + (size_t)OUT_F * 32);    // 64 KB
  char*           rest = (char*)(P + (size_t)MROWS * 32);
  const size_t base   = (size_t)MROWS * IN_F * 2 + (size_t)OUT_F * 32 * 2
                      + (size_t)MROWS * 32 * 4;                // 4,964,352
  const size_t wbf_sz = (size_t)OUT_F * IN_F * 2;              // 90,177,536

  (void)hipMemsetAsync(P, 0, (size_t)MROWS * 32 * sizeof(float), stream);
  convert_k<<<2392, 256, 0, stream>>>(x, U, xbf, Ubf);
  pcalc_k<<<512, 256, 0, stream>>>(x, V, P);

  if (ws_size >= base + wbf_sz) {
    // ---- fast path: pre-dequant W to bf16 (pre-swizzled), clean bf16 GEMM
    unsigned short* Wbf = (unsigned short*)rest;
    wdeq_k<<<1376, 256, 0, stream>>>((const i32x4*)Wq, scale, zero, Wbf);
    gemm_fast<<<688, 512, 49152, stream>>>(xbf, Wbf, P, (const i32x4*)Ubf,
                                           bias, out);
  } else {
    // ---- slow path: round-8 fused dequant GEMM (known-good)
    float* mz = (float*)rest;                                  // 2.82 MB
    mz_k<<<688, 256, 0, stream>>>(scale, zero, (f32x4*)mz);
    milo_gemm<<<688, 512, 49152, stream>>>(xbf, (const i32x4*)Wq,
                                           (const f32x4*)scale, (const f32x4*)mz,
                                           P, (const i32x4*)Ubf, bias, out);
  }
}

// Round 12
// 132.527 us; speedup vs baseline: 1.0764x; 1.0362x over previous
//
#include <hip/hip_runtime.h>
#include <cstdint>

typedef short  s16x8 __attribute__((ext_vector_type(8)));
typedef float  f32x4 __attribute__((ext_vector_type(4)));
typedef int    i32x4 __attribute__((ext_vector_type(4)));
typedef int    i32x2 __attribute__((ext_vector_type(2)));
typedef unsigned short u16x4 __attribute__((ext_vector_type(4)));

#define OUT_F 11008
#define IN_F  4096
#define MROWS 512
#define GQ4   176128   // i32x4 elements per W_q row (704512/4)
#define HALF  5504
#define RMOD  172

__device__ __forceinline__ unsigned short f2bf(float f) {
  unsigned u = __builtin_bit_cast(unsigned, f);
  return (unsigned short)((u + 0x8000u) >> 16);
}
__device__ __forceinline__ float bfbits(unsigned bits) {
  return __builtin_bit_cast(float, bits);
}
__device__ __forceinline__ unsigned cvtpk(float a, float b) {
  unsigned r;
  asm("v_cvt_pk_bf16_f32 %0, %1, %2" : "=v"(r) : "v"(a), "v"(b));
  return r;   // lo = bf16(a), hi = bf16(b)
}

// ---- prelude: bf16-convert x and U ----
__global__ __launch_bounds__(256) void convert_k(const float* __restrict__ x,
                                                 const float* __restrict__ U,
                                                 unsigned short* __restrict__ xbf,
                                                 unsigned short* __restrict__ Ubf) {
  int i = blockIdx.x * 256 + threadIdx.x;
  const int NX = (MROWS * IN_F) / 4;   // 524288
  const int NU = (OUT_F * 32) / 4;     // 88064
  if (i >= NX + NU) return;
  const float* src; unsigned short* dst; int idx;
  if (i < NX) { src = x; dst = xbf; idx = i; }
  else        { src = U; dst = Ubf; idx = i - NX; }
  f32x4 v = *(const f32x4*)(src + (size_t)idx * 4);
  u16x4 o;
  o[0] = f2bf(v[0]); o[1] = f2bf(v[1]); o[2] = f2bf(v[2]); o[3] = f2bf(v[3]);
  *(u16x4*)(dst + (size_t)idx * 4) = o;
}

// ---- slow-path prelude: mz = -(z+128)*s table ----
__global__ __launch_bounds__(256) void mz_k(const float* __restrict__ scale,
                                            const float* __restrict__ zero,
                                            f32x4* __restrict__ mz) {
  int idx = blockIdx.x * 256 + threadIdx.x;
  if (idx >= 176128) return;
  f32x4 s = *(const f32x4*)(scale + (size_t)idx * 4);
  f32x4 z = *(const f32x4*)(zero  + (size_t)idx * 4);
  f32x4 m;
#pragma unroll
  for (int e = 0; e < 4; ++e) m[e] = -(z[e] + 128.f) * s[e];
  mz[idx] = m;
}

// ---- prelude 2: P = x @ V^T (512x32), split-K atomics ----
__global__ __launch_bounds__(256) void pcalc_k(const float* __restrict__ x,
                                               const float* __restrict__ V,
                                               float* __restrict__ P) {
  int m  = (blockIdx.x >> 3) * 8 + (threadIdx.x >> 5);
  int j  = threadIdx.x & 31;
  int k0 = (blockIdx.x & 7) * 512;
  const float* xr = x + (size_t)m * IN_F + k0;
  const float* vr = V + (size_t)j * IN_F + k0;
  float a = 0.f;
#pragma unroll 4
  for (int k = 0; k < 512; k += 4) {
    f32x4 xv = *(const f32x4*)(xr + k);
    f32x4 vv = *(const f32x4*)(vr + k);
    a += xv[0]*vv[0] + xv[1]*vv[1] + xv[2]*vv[2] + xv[3]*vv[3];
  }
  atomicAdd(P + m * 32 + j, a);
}

// ---- fast-path: W dequant to bf16, PRE-SWIZZLED, pure streaming ----
// ROUND-12 RESTRUCTURE: one (j, chunk) per thread (2.82M threads), so each
// wave has 1 contiguous Wq read stream, contiguous scale/zero reads, and
// 2 contiguous write streams -- vs 8 read + 16 write streams per thread
// in the round-11 shape (which ran ~2x its streaming floor).
__global__ __launch_bounds__(256) void wdeq_k(const i32x4* __restrict__ Wq4,
                                              const float* __restrict__ scale,
                                              const float* __restrict__ zero,
                                              unsigned short* __restrict__ Wbf) {
  int n   = blockIdx.x * 256 + threadIdx.x;  // 2,818,048 = 32 j x 88064 ch
  int j   = n / 88064;                       // 0..31
  int ch  = n - j * 88064;                   // chunk of 8 int32 columns
  int r   = ch >> 9;                         // 0..171
  int chL = ch & 511;                        // within-row chunk (i = chL*8)
  const int cc0 = ch * 8;
  f32x4 s0 = *(const f32x4*)(scale + cc0);
  f32x4 s1 = *(const f32x4*)(scale + cc0 + 4);
  f32x4 z0 = *(const f32x4*)(zero + cc0);
  f32x4 z1 = *(const f32x4*)(zero + cc0 + 4);
  i32x4 w0 = Wq4[(size_t)j * GQ4 + ch * 2];
  i32x4 w1 = Wq4[(size_t)j * GQ4 + ch * 2 + 1];
  float h[8], l[8];
#pragma unroll
  for (int e = 0; e < 8; ++e) {
    int   v = (e < 4) ? w0[e] : w1[e - 4];
    float s = (e < 4) ? s0[e] : s1[e - 4];
    float z = (e < 4) ? z0[e] : z1[e - 4];
    float m = -(z + 128.f) * s;
    float qh = bfbits(0x43000000u | (((unsigned)v & 0xF0u) << 12));
    float ql = bfbits(0x43000000u | (((unsigned)v & 0x0Fu) << 16));
    h[e] = __builtin_fmaf(qh, s, m);
    l[e] = __builtin_fmaf(ql, s, m);
  }
  i32x4 hh = { (int)cvtpk(h[0], h[1]), (int)cvtpk(h[2], h[3]),
               (int)cvtpk(h[4], h[5]), (int)cvtpk(h[6], h[7]) };
  i32x4 ll = { (int)cvtpk(l[0], l[1]), (int)cvtpk(l[2], l[3]),
               (int)cvtpk(l[4], l[5]), (int)cvtpk(l[6], l[7]) };
  int o  = j * RMOD + r;
  int o2 = o + HALF;
  unsigned sc  = ((unsigned)chL & ~7u) | (((unsigned)chL ^ (unsigned)o)  & 7u);
  unsigned sc2 = ((unsigned)chL & ~7u) | (((unsigned)chL ^ (unsigned)o2) & 7u);
  *(i32x4*)(Wbf + (size_t)o  * IN_F + sc  * 8) = hh;
  *(i32x4*)(Wbf + (size_t)o2 * IN_F + sc2 * 8) = ll;
}

// ---- fast-path GEMM: bf16, tile 128m x 128o, 512 thr (8 waves 2m x 4o) ----
// ROUND-12: tile doubled on m (was 64x128): 16 MFMA per K-step per wave,
// 2x barrier amortization. LDS 64KB: A [128][64]x2 + B [128][64]x2.
// Grid 344 = 8 XCD x 43 contiguous-L mapping. Same swizzle conventions.
__global__ __launch_bounds__(512, 4) void gemm_fast(
    const unsigned short* __restrict__ xbf,
    const unsigned short* __restrict__ Wbf,
    const float*          __restrict__ Pf,
    const i32x4*          __restrict__ Ubf4,
    const float*          __restrict__ bias,
    float*                __restrict__ out)
{
  extern __shared__ __align__(16) unsigned short smem[];
  // A bufs: smem + buf*8192 shorts; B bufs: smem + 16384 + buf*8192 shorts

  const int tid  = threadIdx.x;
  const int lane = tid & 63;
  const int wid  = tid >> 6;   // 0..7
  const int wm   = wid >> 2;   // 0..1: 64-row m sub-tile
  const int wn   = wid & 3;    // 0..3: 32-row o sub-tile

  const int b  = blockIdx.x;
  const int L  = (b & 7) * 43 + (b >> 3);
  const int gn = L >> 2;          // 0..85  -> o0 = gn*128
  const int gm = L & 3;           // 0..3   -> m0 = gm*128
  const int m0 = gm * 128;
  const int o0 = gn * 128;

  // A staging: pre-swizzled global source, linear LDS dest
  unsigned a_src[2];
#pragma unroll
  for (int it = 0; it < 2; ++it)
    a_src[it] = (unsigned)(m0 + it * 64 + (tid >> 3)) * IN_F +
                (((tid & 7) ^ ((tid >> 3) & 7)) * 8);
  // B staging: Wbf already swizzled -> linear source, linear dest
  size_t b_src[2];
#pragma unroll
  for (int it = 0; it < 2; ++it)
    b_src[it] = (size_t)(o0 + it * 64 + (tid >> 3)) * IN_F + (tid & 7) * 8;

  const int akey   = (lane & 7) << 3;
  const int a_base = (wm * 64 + (lane & 15)) * 64 + ((lane >> 4) * 8);
  const int b_base = (wn * 32 + (lane & 15)) * 64 + ((lane >> 4) * 8);

  f32x4 acc[4][2];
  {
    f32x4 zf = {0.f, 0.f, 0.f, 0.f};
#pragma unroll
    for (int i = 0; i < 4; ++i)
#pragma unroll
      for (int j = 0; j < 2; ++j) acc[i][j] = zf;
  }
  f32x4 pf0, pf1; i32x4 uuF;

  auto issueA = [&](int buf, int k0s) {
    unsigned short* Adst = smem + buf * 8192;
#pragma unroll
    for (int it = 0; it < 2; ++it) {
      __builtin_amdgcn_global_load_lds(
          (const __attribute__((address_space(1))) unsigned int*)(xbf + a_src[it] + k0s),
          (__attribute__((address_space(3))) unsigned int*)(Adst + it * 4096 + tid * 8),
          16, 0, 0);
    }
  };
  auto issueB = [&](int buf, int k0s) {
    unsigned short* Bdst = smem + 16384 + buf * 8192;
#pragma unroll
    for (int it = 0; it < 2; ++it) {
      __builtin_amdgcn_global_load_lds(
          (const __attribute__((address_space(1))) unsigned int*)(Wbf + b_src[it] + k0s),
          (__attribute__((address_space(3))) unsigned int*)(Bdst + it * 4096 + tid * 8),
          16, 0, 0);
    }
  };
  auto compute = [&](int buf) {
    const unsigned short* Ac = smem + buf * 8192;
    const unsigned short* Bc = smem + 16384 + buf * 8192;
    __builtin_amdgcn_s_setprio(1);
#pragma unroll
    for (int kk = 0; kk < 64; kk += 32) {
      s16x8 av[4], bv[2];
#pragma unroll
      for (int f = 0; f < 4; ++f)
        av[f] = *(const s16x8*)(Ac + ((a_base + f * 1024 + kk) ^ akey));
#pragma unroll
      for (int f = 0; f < 2; ++f)
        bv[f] = *(const s16x8*)(Bc + ((b_base + f * 1024 + kk) ^ akey));
#pragma unroll
      for (int i = 0; i < 4; ++i)
#pragma unroll
        for (int j = 0; j < 2; ++j)
          acc[i][j] = __builtin_amdgcn_mfma_f32_16x16x32_bf16(av[i], bv[j], acc[i][j], 0, 0, 0);
    }
    __builtin_amdgcn_s_setprio(0);
  };
  auto loadF = [&]() {
    int row = tid >> 2, h4 = tid & 3;
    pf0 = *(const f32x4*)(Pf + (m0 + row) * 32 + h4 * 8);
    pf1 = *(const f32x4*)(Pf + (m0 + row) * 32 + h4 * 8 + 4);
    uuF = Ubf4[(size_t)(o0 + row) * 4 + h4];
  };
  auto writeF = [&](int buf) {
    unsigned short* An = smem + buf * 8192;
    unsigned short* Bn = smem + 16384 + buf * 8192;
    i32x4 zi = {0, 0, 0, 0};
    int row = tid >> 2, h4 = tid & 3, key = row & 7;
    i32x4 t4 = { (int)cvtpk(pf0[0], pf0[1]), (int)cvtpk(pf0[2], pf0[3]),
                 (int)cvtpk(pf1[0], pf1[1]), (int)cvtpk(pf1[2], pf1[3]) };
    *(i32x4*)(An + row * 64 + ((h4 ^ key) * 8))       = t4;   // P cols 0..31
    *(i32x4*)(An + row * 64 + (((h4 + 4) ^ key) * 8)) = zi;   // zero 32..63
    *(i32x4*)(Bn + row * 64 + ((h4 ^ key) * 8))       = uuF;  // U cols 0..31
    *(i32x4*)(Bn + row * 64 + (((h4 + 4) ^ key) * 8)) = zi;
  };

  // ---- prologue ----
  issueA(0, 0);
  issueB(0, 0);
  __syncthreads();

  // ---- main K loop: 64 tiles of BK=64 ----
  for (int t = 0; t < 63; ++t) {
    int cur = t & 1, nxt = cur ^ 1;
    issueA(nxt, (t + 1) * 64);
    issueB(nxt, (t + 1) * 64);
    compute(cur);
    __syncthreads();
  }
  // ---- tile 63 + low-rank extra K-step ----
  loadF();
  compute(1);
  writeF(0);
  __syncthreads();
  compute(0);

  // ---- epilogue: bias + store (Wbf in final row order) ----
#pragma unroll
  for (int fn = 0; fn < 2; ++fn) {
    int o = o0 + wn * 32 + fn * 16 + (lane & 15);
    float bv = bias[o];
#pragma unroll
    for (int fm = 0; fm < 4; ++fm) {
      int m = m0 + wm * 64 + fm * 16 + ((lane >> 4) << 2);
#pragma unroll
      for (int j = 0; j < 4; ++j)
        out[(size_t)(m + j) * OUT_F + o] = acc[fm][fn][j] + bv;
    }
  }
}

// ================= slow-path fallback: round-8 fused kernel =================
__global__ __launch_bounds__(512, 6) void milo_gemm(
    const unsigned short* __restrict__ xbf,
    const i32x4*          __restrict__ Wq4,
    const f32x4*          __restrict__ Sc4,
    const f32x4*          __restrict__ Mz4,
    const float*          __restrict__ Pf,
    const i32x4*          __restrict__ Ubf4,
    const float*          __restrict__ bias,
    float*                __restrict__ out)
{
  extern __shared__ __align__(16) unsigned short smem[];
  const int tid  = threadIdx.x;
  const int lane = tid & 63;
  const int wid  = tid >> 6;
  const int wm   = wid >> 1;
  const int wn   = wid & 1;
  const int b  = blockIdx.x;
  const int L  = (b & 7) * 86 + (b >> 3);
  const int gn = L >> 2;
  const int gm = L & 3;
  const int m0 = gm * 128;
  const int o0 = gn * 32;
  const int tr = tid >> 4;
  unsigned wq_off, sc_off;
  {
    int o = o0 + tr;
    int g = o / RMOD;
    int r = o - g * RMOD;
    wq_off = (unsigned)g * GQ4 + (unsigned)r * 1024u + (tid & 15);
    sc_off = (unsigned)r * 1024u + (tid & 15);
  }
  unsigned a_src[2];
#pragma unroll
  for (int it = 0; it < 2; ++it) {
    int row   = wid * 16 + it * 8 + (lane >> 3);
    int chunk = (lane & 7) ^ (lane >> 3);
    a_src[it] = (unsigned)(m0 + row) * IN_F + chunk * 8;
  }
  const int akey   = (lane & 7) << 3;
  const int a_base = (wm * 32 + (lane & 15)) * 64 + ((lane >> 4) * 8);
  const int b_base = (wn * 32 + (lane & 15)) * 64 + ((lane >> 4) * 8);
  f32x4 acc[2][2];
  {
    f32x4 zf = {0.f, 0.f, 0.f, 0.f};
#pragma unroll
    for (int i = 0; i < 2; ++i)
#pragma unroll
      for (int j = 0; j < 2; ++j) acc[i][j] = zf;
  }
  i32x4 wq; f32x4 s4, mz4;
  f32x4 pf[2]; i32x4 uuF;
  auto issueA = [&](int buf, int k0s) {
    unsigned short* Adst = smem + buf * 8192;
#pragma unroll
    for (int it = 0; it < 2; ++it) {
      __builtin_amdgcn_global_load_lds(
          (const __attribute__((address_space(1))) unsigned int*)(xbf + a_src[it] + k0s),
          (__attribute__((address_space(3))) unsigned int*)(Adst + (wid * 16 + it * 8) * 64),
          16, 0, 0);
    }
  };
  auto loadB = [&](int kq) {
    wq  = Wq4[wq_off + kq];
    s4  = Sc4[sc_off + kq];
    mz4 = Mz4[sc_off + kq];
  };
  auto writeB = [&](int buf) {
    unsigned short* Bn = smem + 16384 + buf * 4096;
    int scol = ((tid & 15) * 4) ^ ((tr & 7) << 3);
    float h[4], l[4];
#pragma unroll
    for (int e = 0; e < 4; ++e) {
      int v = wq[e];
      float qh = bfbits(0x43000000u | (((unsigned)v & 0xF0u) << 12));
      float ql = bfbits(0x43000000u | (((unsigned)v & 0x0Fu) << 16));
      h[e] = __builtin_fmaf(qh, s4[e], mz4[e]);
      l[e] = __builtin_fmaf(ql, s4[e], mz4[e]);
    }
    i32x2 hh = { (int)cvtpk(h[0], h[1]), (int)cvtpk(h[2], h[3]) };
    i32x2 ll = { (int)cvtpk(l[0], l[1]), (int)cvtpk(l[2], l[3]) };
    *(i32x2*)(Bn + tr * 64 + scol)        = hh;
    *(i32x2*)(Bn + (tr + 32) * 64 + scol) = ll;
  };
  auto loadF = [&]() {
    int row = tid >> 2, h4 = tid & 3;
#pragma unroll
    for (int q = 0; q < 2; ++q)
      pf[q] = *(const f32x4*)(Pf + (m0 + row) * 32 + h4 * 8 + q * 4);
    int rw = tid >> 3, h8 = tid & 7;
    int oc = (rw < 32) ? (o0 + rw) : (HALF + o0 + rw - 32);
    uuF = Ubf4[oc * 4 + (h8 & 3)];
  };
  auto writeF = [&](int buf) {
    unsigned short* An = smem + buf * 8192;
    unsigned short* Bn = smem + 16384 + buf * 4096;
    i32x4 zi = {0, 0, 0, 0};
    {
      int row = tid >> 2, h4 = tid & 3;
      int key = (row & 7) << 3;
      i32x4 t4 = { (int)cvtpk(pf[0][0], pf[0][1]), (int)cvtpk(pf[0][2], pf[0][3]),
                   (int)cvtpk(pf[1][0], pf[1][1]), (int)cvtpk(pf[1][2], pf[1][3]) };
      *(i32x4*)(An + row * 64 + ((h4 * 8) ^ key))      = t4;
      *(i32x4*)(An + row * 64 + ((32 + h4 * 8) ^ key)) = zi;
    }
    {
      int rw = tid >> 3, h8 = tid & 7;
      int key = (rw & 7) << 3;
      *(i32x4*)(Bn + rw * 64 + ((h8 * 8) ^ key)) = (h8 < 4) ? uuF : zi;
    }
  };
  auto compute = [&](int buf) {
    const unsigned short* Ac = smem + buf * 8192;
    const unsigned short* Bc = smem + 16384 + buf * 4096;
    __builtin_amdgcn_s_setprio(1);
#pragma unroll
    for (int kk = 0; kk < 64; kk += 32) {
      s16x8 av[2], bv[2];
#pragma unroll
      for (int f = 0; f < 2; ++f)
        av[f] = *(const s16x8*)(Ac + ((a_base + f * 1024 + kk) ^ akey));
#pragma unroll
      for (int f = 0; f < 2; ++f)
        bv[f] = *(const s16x8*)(Bc + ((b_base + f * 1024 + kk) ^ akey));
#pragma unroll
      for (int i = 0; i < 2; ++i)
#pragma unroll
        for (int j = 0; j < 2; ++j)
          acc[i][j] = __builtin_amdgcn_mfma_f32_16x16x32_bf16(av[i], bv[j], acc[i][j], 0, 0, 0);
    }
    __builtin_amdgcn_s_setprio(0);
  };
  loadB(0);
  issueA(0, 0);
  writeB(0);
  __syncthreads();
  for (int t = 0; t < 63; ++t) {
    int cur = t & 1, nxt = cur ^ 1;
    loadB((t + 1) * 16);
    issueA(nxt, (t + 1) * 64);
    compute(cur);
    writeB(nxt);
    __syncthreads();
  }
  loadF();
  compute(1);
  writeF(0);
  __syncthreads();
  compute(0);
#pragma unroll
  for (int fn = 0; fn < 2; ++fn) {
    int c = wn * 32 + fn * 16 + (lane & 15);
    int o = (c < 32) ? (o0 + c) : (HALF + o0 + (c - 32));
    float bv = bias[o];
#pragma unroll
    for (int fm = 0; fm < 2; ++fm) {
      int m = m0 + wm * 32 + fm * 16 + ((lane >> 4) << 2);
#pragma unroll
      for (int j = 0; j < 4; ++j)
        out[(size_t)(m + j) * OUT_F + o] = acc[fm][fn][j] + bv;
    }
  }
}

extern "C" void kernel_launch(void* const* d_in, const int* in_sizes, int n_in,
                              void* d_out, int out_size, void* d_ws, size_t ws_size,
                              hipStream_t stream) {
  const float* x     = (const float*)d_in[0];
  const int*   Wq    = (const int*)d_in[1];
  const float* scale = (const float*)d_in[2];
  const float* zero  = (const float*)d_in[3];
  const float* U     = (const float*)d_in[4];
  const float* V     = (const float*)d_in[5];
  const float* bias  = (const float*)d_in[6];
  float* out = (float*)d_out;

  unsigned short* xbf = (unsigned short*)d_ws;                 // 4 MB
  unsigned short* Ubf = xbf + (size_t)MROWS * IN_F;            // 704 KB
  float*          P   = (float*)(Ubf + (size_t)OUT_F * 32);    // 64 KB
  char*           rest = (char*)(P + (size_t)MROWS * 32);
  const size_t base   = (size_t)MROWS * IN_F * 2 + (size_t)OUT_F * 32 * 2
                      + (size_t)MROWS * 32 * 4;                // 4,964,352
  const size_t wbf_sz = (size_t)OUT_F * IN_F * 2;              // 90,177,536

  (void)hipMemsetAsync(P, 0, (size_t)MROWS * 32 * sizeof(float), stream);
  convert_k<<<2392, 256, 0, stream>>>(x, U, xbf, Ubf);
  pcalc_k<<<512, 256, 0, stream>>>(x, V, P);

  if (ws_size >= base + wbf_sz) {
    // ---- fast path: streaming pre-dequant + 128x128 bf16 GEMM
    unsigned short* Wbf = (unsigned short*)rest;
    wdeq_k<<<11008, 256, 0, stream>>>((const i32x4*)Wq, scale, zero, Wbf);
    gemm_fast<<<344, 512, 65536, stream>>>(xbf, Wbf, P, (const i32x4*)Ubf,
                                           bias, out);
  } else {
    // ---- slow path: round-8 fused dequant GEMM (known-good)
    float* mz = (float*)rest;                                  // 2.82 MB
    mz_k<<<688, 256, 0, stream>>>(scale, zero, (f32x4*)mz);
    milo_gemm<<<688, 512, 49152, stream>>>(xbf, (const i32x4*)Wq,
                                           (const f32x4*)scale, (const f32x4*)mz,
                                           P, (const i32x4*)Ubf, bias, out);
  }
}